// Round 1
// baseline (4062.036 us; speedup 1.0000x reference)
//
#include <hip/hip_runtime.h>
#include <hip/hip_bf16.h>
#include <math.h>

#define DIM 1024
#define DSTATE 16
#define DCONV 4
#define BATCH 2
#define TLEN 4096

// ---------------------------------------------------------------------------
// Tiled f32 GEMM: C[M,N] = A[M,K] @ B[K,N]  (row-major all)
// 64x64 block tile, BK=16, 256 threads, 4x4 per thread.
// EPI: 0 = plain store, 1 = softplus(acc + bias[n])
// M,N multiples of 64; K multiple of 16. No bounds checks.
// ---------------------------------------------------------------------------
template <int EPI>
__global__ __launch_bounds__(256) void gemm_f32(
    const float* __restrict__ A, const float* __restrict__ B,
    const float* __restrict__ bias, float* __restrict__ C,
    int M, int N, int K)
{
    __shared__ float As[16][64];   // As[k][m]
    __shared__ float Bs[16][64];   // Bs[k][n]

    const int tid = threadIdx.x;
    const int tx = tid & 15;       // col group
    const int ty = tid >> 4;       // row group
    const int row0 = blockIdx.y * 64;
    const int col0 = blockIdx.x * 64;

    float acc[4][4];
#pragma unroll
    for (int i = 0; i < 4; ++i)
#pragma unroll
        for (int j = 0; j < 4; ++j) acc[i][j] = 0.f;

    const int ar = tid >> 2;             // 0..63 (m within tile)
    const int ak = (tid & 3) << 2;       // 0,4,8,12 (k within tile)
    const int bk = tid >> 4;             // 0..15 (k within tile)
    const int bn = (tid & 15) << 2;      // 0..60 (n within tile)

    for (int k0 = 0; k0 < K; k0 += 16) {
        float4 av = *(const float4*)&A[(size_t)(row0 + ar) * K + k0 + ak];
        float4 bv = *(const float4*)&B[(size_t)(k0 + bk) * N + col0 + bn];
        __syncthreads();
        As[ak + 0][ar] = av.x;
        As[ak + 1][ar] = av.y;
        As[ak + 2][ar] = av.z;
        As[ak + 3][ar] = av.w;
        *(float4*)&Bs[bk][bn] = bv;
        __syncthreads();
#pragma unroll
        for (int k = 0; k < 16; ++k) {
            float a[4], b[4];
            *(float4*)a = *(const float4*)&As[k][ty * 4];
            *(float4*)b = *(const float4*)&Bs[k][tx * 4];
#pragma unroll
            for (int i = 0; i < 4; ++i)
#pragma unroll
                for (int j = 0; j < 4; ++j)
                    acc[i][j] = fmaf(a[i], b[j], acc[i][j]);
        }
    }

#pragma unroll
    for (int i = 0; i < 4; ++i) {
        float4 out;
        float* o = (float*)&out;
#pragma unroll
        for (int j = 0; j < 4; ++j) {
            float v = acc[i][j];
            if (EPI == 1) {
                v += bias[col0 + tx * 4 + j];
                // softplus
                v = (v > 20.f) ? v : log1pf(__expf(v));
            }
            o[j] = v;
        }
        *(float4*)&C[(size_t)(row0 + ty * 4 + i) * N + col0 + tx * 4] = out;
    }
}

// ---------------------------------------------------------------------------
// Depthwise causal conv (window 4) + bias + SiLU.
// xz layout: (B*T, 2*DIM); x-half at [0,DIM). Output x_in: (B*T, DIM).
// ---------------------------------------------------------------------------
__global__ __launch_bounds__(256) void conv_silu_kernel(
    const float* __restrict__ xz, const float* __restrict__ conv_w,
    const float* __restrict__ conv_b, float* __restrict__ x_in)
{
    size_t idx = (size_t)blockIdx.x * 256 + threadIdx.x;   // over B*T*DIM
    int d = (int)(idx & (DIM - 1));
    size_t bt = idx >> 10;                                  // b*T + t
    int t = (int)(bt & (TLEN - 1));

    float acc = conv_b[d];
#pragma unroll
    for (int k = 0; k < DCONV; ++k) {
        int tt = t - (DCONV - 1) + k;
        if (tt >= 0) {
            acc = fmaf(xz[(bt - (DCONV - 1) + k) * (2 * DIM) + d],
                       conv_w[d * DCONV + k], acc);
        }
    }
    // silu
    float s = acc / (1.f + __expf(-acc));
    x_in[idx] = s;
}

// ---------------------------------------------------------------------------
// BC = x_in(B*T, DIM) @ W_x(DIM, 2*DSTATE)   (N = 32)
// 8 rows per block; 32 threads per row.
// ---------------------------------------------------------------------------
__global__ __launch_bounds__(256) void bc_kernel(
    const float* __restrict__ x_in, const float* __restrict__ W_x,
    float* __restrict__ BC)
{
    int n = threadIdx.x & 31;
    int ml = threadIdx.x >> 5;
    size_t m = (size_t)blockIdx.x * 8 + ml;
    const float* xr = &x_in[m * DIM];
    float acc = 0.f;
#pragma unroll 4
    for (int k = 0; k < DIM; ++k) {
        acc = fmaf(xr[k], W_x[k * (2 * DSTATE) + n], acc);
    }
    BC[m * (2 * DSTATE) + n] = acc;
}

// ---------------------------------------------------------------------------
// Selective scan + D skip + z-gating.
// One lane per (b, d, n). 16 lanes per channel group; 16 groups per block.
// Writes y_gated over x_in buffer (safe: in-wave read-before-write at each t).
// ---------------------------------------------------------------------------
__global__ __launch_bounds__(256) void scan_kernel(
    const float* __restrict__ dt, const float* __restrict__ BC,
    const float* __restrict__ xz, const float* __restrict__ A_log,
    const float* __restrict__ D_param, float* __restrict__ x_in_y)
{
    const int lane = threadIdx.x;
    const int n = lane & 15;
    const int g = lane >> 4;                 // 0..15
    const int b = blockIdx.x >> 6;           // 0..1
    const int dblk = blockIdx.x & 63;        // 0..63
    const int d = dblk * 16 + g;

    const float A = -__expf(A_log[d * DSTATE + n]);
    const float Dp = D_param[d];

    float h = 0.f;
    const size_t base = (size_t)b * TLEN;
    for (int t = 0; t < TLEN; ++t) {
        const size_t r = base + t;
        const float dtv = dt[r * DIM + d];
        const float xv = x_in_y[r * DIM + d];
        const float Bv = BC[r * (2 * DSTATE) + n];
        const float Cv = BC[r * (2 * DSTATE) + DSTATE + n];

        const float a = __expf(dtv * A);
        h = fmaf(a, h, dtv * Bv * xv);

        float p = h * Cv;
        p += __shfl_xor(p, 1, 16);
        p += __shfl_xor(p, 2, 16);
        p += __shfl_xor(p, 4, 16);
        p += __shfl_xor(p, 8, 16);

        if (n == 0) {
            const float zv = xz[r * (2 * DIM) + DIM + d];
            const float y = p + Dp * xv;
            const float sig = 1.f / (1.f + __expf(-zv));
            x_in_y[r * DIM + d] = y * (zv * sig);
        }
    }
}

// ---------------------------------------------------------------------------
// Launch
// ---------------------------------------------------------------------------
extern "C" void kernel_launch(void* const* d_in, const int* in_sizes, int n_in,
                              void* d_out, int out_size, void* d_ws, size_t ws_size,
                              hipStream_t stream)
{
    const float* x      = (const float*)d_in[0];
    const float* W_in   = (const float*)d_in[1];
    const float* conv_w = (const float*)d_in[2];
    const float* conv_b = (const float*)d_in[3];
    const float* A_log  = (const float*)d_in[4];
    const float* D_par  = (const float*)d_in[5];
    const float* W_x    = (const float*)d_in[6];
    const float* W_dt   = (const float*)d_in[7];
    const float* b_dt   = (const float*)d_in[8];
    const float* W_out  = (const float*)d_in[9];
    float* out = (float*)d_out;

    const size_t BT = (size_t)BATCH * TLEN;          // 8192
    float* ws = (float*)d_ws;
    float* xz   = ws;                                // BT * 2048
    float* x_in = xz + BT * (2 * DIM);               // BT * 1024 (later y_gated)
    float* dt   = x_in + BT * DIM;                   // BT * 1024
    float* BC   = dt + BT * DIM;                     // BT * 32

    // 1) xz = x @ W_in   (8192 x 1024 x 2048)
    {
        dim3 grid(2 * DIM / 64, BT / 64);
        gemm_f32<0><<<grid, 256, 0, stream>>>(x, W_in, nullptr, xz,
                                              (int)BT, 2 * DIM, DIM);
    }
    // 2) conv + silu -> x_in
    {
        size_t total = BT * DIM;
        conv_silu_kernel<<<(int)(total / 256), 256, 0, stream>>>(xz, conv_w, conv_b, x_in);
    }
    // 3) dt = softplus(x_in @ W_dt + b_dt)
    {
        dim3 grid(DIM / 64, BT / 64);
        gemm_f32<1><<<grid, 256, 0, stream>>>(x_in, W_dt, b_dt, dt,
                                              (int)BT, DIM, DIM);
    }
    // 4) BC = x_in @ W_x
    {
        bc_kernel<<<(int)(BT / 8), 256, 0, stream>>>(x_in, W_x, BC);
    }
    // 5) scan + gating -> y_gated (in-place over x_in)
    {
        scan_kernel<<<BATCH * (DIM / 16), 256, 0, stream>>>(dt, BC, xz, A_log, D_par, x_in);
    }
    // 6) out = y_gated @ W_out
    {
        dim3 grid(DIM / 64, BT / 64);
        gemm_f32<0><<<grid, 256, 0, stream>>>(x_in, W_out, nullptr, out,
                                              (int)BT, DIM, DIM);
    }
}

// Round 2
// 1415.395 us; speedup vs baseline: 2.8699x; 2.8699x over previous
//
#include <hip/hip_runtime.h>
#include <hip/hip_bf16.h>
#include <math.h>

#define DIM 1024
#define DSTATE 16
#define DCONV 4
#define BATCH 2
#define TLEN 4096
#define NC 32            // time chunks
#define LC (TLEN / NC)   // 128 steps per chunk

// Strided index into dead x-half columns of xz: logical index i -> byte layout
// row (i>>10) of xz, column (i&1023). Rows 0..2047 used; z-half untouched.
__device__ __forceinline__ size_t ps_addr(size_t i) {
    return ((i >> 10) << 11) | (i & 1023);
}

// ---------------------------------------------------------------------------
// Tiled f32 GEMM: C[M,N] = A[M,K] @ B[K,N]  (row-major all)
// 64x64 block tile, BK=16, 256 threads, 4x4 per thread.
// EPI: 0 = plain store, 1 = softplus(acc + bias[n])
// ---------------------------------------------------------------------------
template <int EPI>
__global__ __launch_bounds__(256) void gemm_f32(
    const float* __restrict__ A, const float* __restrict__ B,
    const float* __restrict__ bias, float* __restrict__ C,
    int M, int N, int K)
{
    __shared__ float As[16][64];   // As[k][m]
    __shared__ float Bs[16][64];   // Bs[k][n]

    const int tid = threadIdx.x;
    const int tx = tid & 15;
    const int ty = tid >> 4;
    const int row0 = blockIdx.y * 64;
    const int col0 = blockIdx.x * 64;

    float acc[4][4];
#pragma unroll
    for (int i = 0; i < 4; ++i)
#pragma unroll
        for (int j = 0; j < 4; ++j) acc[i][j] = 0.f;

    const int ar = tid >> 2;
    const int ak = (tid & 3) << 2;
    const int bk = tid >> 4;
    const int bn = (tid & 15) << 2;

    for (int k0 = 0; k0 < K; k0 += 16) {
        float4 av = *(const float4*)&A[(size_t)(row0 + ar) * K + k0 + ak];
        float4 bv = *(const float4*)&B[(size_t)(k0 + bk) * N + col0 + bn];
        __syncthreads();
        As[ak + 0][ar] = av.x;
        As[ak + 1][ar] = av.y;
        As[ak + 2][ar] = av.z;
        As[ak + 3][ar] = av.w;
        *(float4*)&Bs[bk][bn] = bv;
        __syncthreads();
#pragma unroll
        for (int k = 0; k < 16; ++k) {
            float a[4], b[4];
            *(float4*)a = *(const float4*)&As[k][ty * 4];
            *(float4*)b = *(const float4*)&Bs[k][tx * 4];
#pragma unroll
            for (int i = 0; i < 4; ++i)
#pragma unroll
                for (int j = 0; j < 4; ++j)
                    acc[i][j] = fmaf(a[i], b[j], acc[i][j]);
        }
    }

#pragma unroll
    for (int i = 0; i < 4; ++i) {
        float4 out;
        float* o = (float*)&out;
#pragma unroll
        for (int j = 0; j < 4; ++j) {
            float v = acc[i][j];
            if (EPI == 1) {
                v += bias[col0 + tx * 4 + j];
                v = (v > 20.f) ? v : log1pf(__expf(v));
            }
            o[j] = v;
        }
        *(float4*)&C[(size_t)(row0 + ty * 4 + i) * N + col0 + tx * 4] = out;
    }
}

// ---------------------------------------------------------------------------
// Depthwise causal conv (window 4) + bias + SiLU.
// ---------------------------------------------------------------------------
__global__ __launch_bounds__(256) void conv_silu_kernel(
    const float* __restrict__ xz, const float* __restrict__ conv_w,
    const float* __restrict__ conv_b, float* __restrict__ x_in)
{
    size_t idx = (size_t)blockIdx.x * 256 + threadIdx.x;
    int d = (int)(idx & (DIM - 1));
    size_t bt = idx >> 10;
    int t = (int)(bt & (TLEN - 1));

    float acc = conv_b[d];
#pragma unroll
    for (int k = 0; k < DCONV; ++k) {
        int tt = t - (DCONV - 1) + k;
        if (tt >= 0) {
            acc = fmaf(xz[(bt - (DCONV - 1) + k) * (2 * DIM) + d],
                       conv_w[d * DCONV + k], acc);
        }
    }
    float s = acc / (1.f + __expf(-acc));
    x_in[idx] = s;
}

// ---------------------------------------------------------------------------
// BC = x_in(B*T, DIM) @ W_x(DIM, 2*DSTATE)
// ---------------------------------------------------------------------------
__global__ __launch_bounds__(256) void bc_kernel(
    const float* __restrict__ x_in, const float* __restrict__ W_x,
    float* __restrict__ BC)
{
    int n = threadIdx.x & 31;
    int ml = threadIdx.x >> 5;
    size_t m = (size_t)blockIdx.x * 8 + ml;
    const float* xr = &x_in[m * DIM];
    float acc = 0.f;
#pragma unroll 4
    for (int k = 0; k < DIM; ++k) {
        acc = fmaf(xr[k], W_x[k * (2 * DSTATE) + n], acc);
    }
    BC[m * (2 * DSTATE) + n] = acc;
}

// ---------------------------------------------------------------------------
// Scan pass A: per (b, d, n, chunk): local scan from h=0 -> S, decay prod -> P
// Block: 256 threads = 16 groups of 16 lanes (n). Grid: b * NC * (DIM/16).
// ---------------------------------------------------------------------------
__global__ __launch_bounds__(256) void scan_pass_a(
    const float* __restrict__ dt, const float* __restrict__ BC,
    const float* __restrict__ x_in, const float* __restrict__ A_log,
    float* __restrict__ Pb, float* __restrict__ Sb)
{
    const int tid = threadIdx.x;
    const int n = tid & 15;
    const int g = tid >> 4;                  // 0..15
    int blk = blockIdx.x;
    const int dblk = blk & 63;  blk >>= 6;   // DIM/16 = 64
    const int c = blk & (NC - 1); blk >>= 5; // NC = 32
    const int b = blk;
    const int d = dblk * 16 + g;

    const float A = -__expf(A_log[d * DSTATE + n]);

    float h = 0.f, sdt = 0.f;
    const size_t base = (size_t)b * TLEN + (size_t)c * LC;
    for (int t = 0; t < LC; ++t) {
        const size_t r = base + t;
        const float dtv = dt[r * DIM + d];
        const float xv  = x_in[r * DIM + d];
        const float Bv  = BC[r * (2 * DSTATE) + n];
        sdt += dtv;
        const float a = __expf(dtv * A);
        h = fmaf(a, h, dtv * Bv * xv);
    }
    const size_t o = (((size_t)c * BATCH + b) * DIM + d) * DSTATE + n;
    Pb[ps_addr(o)] = __expf(A * sdt);
    Sb[ps_addr(o)] = h;
}

// ---------------------------------------------------------------------------
// Scan pass B: per (b,d,n): sequential combine over NC chunks.
// Overwrites P[c] with the INCOMING state of chunk c.
// ---------------------------------------------------------------------------
__global__ __launch_bounds__(256) void scan_pass_b(
    float* __restrict__ Pb, const float* __restrict__ Sb)
{
    const size_t idx = (size_t)blockIdx.x * 256 + threadIdx.x;  // B*DIM*16
    float h = 0.f;
#pragma unroll 4
    for (int c = 0; c < NC; ++c) {
        const size_t o = (size_t)c * (BATCH * DIM * DSTATE) + idx;
        const size_t a = ps_addr(o);
        const float p = Pb[a];
        const float s = Sb[a];
        Pb[a] = h;                 // incoming state for chunk c
        h = fmaf(p, h, s);
    }
}

// ---------------------------------------------------------------------------
// Scan pass C: re-run local scan seeded with incoming state; y reduction over
// n (16-wide shuffle), D skip, z-gating; write y over x_in (in place).
// ---------------------------------------------------------------------------
__global__ __launch_bounds__(256) void scan_pass_c(
    const float* __restrict__ dt, const float* __restrict__ BC,
    const float* __restrict__ xz, const float* __restrict__ A_log,
    const float* __restrict__ D_param, const float* __restrict__ Hin,
    float* __restrict__ x_in_y)
{
    const int tid = threadIdx.x;
    const int n = tid & 15;
    const int g = tid >> 4;
    int blk = blockIdx.x;
    const int dblk = blk & 63;  blk >>= 6;
    const int c = blk & (NC - 1); blk >>= 5;
    const int b = blk;
    const int d = dblk * 16 + g;

    const float A = -__expf(A_log[d * DSTATE + n]);
    const float Dp = D_param[d];

    const size_t o = (((size_t)c * BATCH + b) * DIM + d) * DSTATE + n;
    float h = Hin[ps_addr(o)];

    const size_t base = (size_t)b * TLEN + (size_t)c * LC;
    for (int t = 0; t < LC; ++t) {
        const size_t r = base + t;
        const float dtv = dt[r * DIM + d];
        const float xv  = x_in_y[r * DIM + d];
        const float Bv  = BC[r * (2 * DSTATE) + n];
        const float Cv  = BC[r * (2 * DSTATE) + DSTATE + n];

        const float a = __expf(dtv * A);
        h = fmaf(a, h, dtv * Bv * xv);

        float p = h * Cv;
        p += __shfl_xor(p, 1, 16);
        p += __shfl_xor(p, 2, 16);
        p += __shfl_xor(p, 4, 16);
        p += __shfl_xor(p, 8, 16);

        if (n == 0) {
            const float zv = xz[r * (2 * DIM) + DIM + d];
            const float y = p + Dp * xv;
            const float sig = 1.f / (1.f + __expf(-zv));
            x_in_y[r * DIM + d] = y * (zv * sig);
        }
    }
}

// ---------------------------------------------------------------------------
// Launch
// ---------------------------------------------------------------------------
extern "C" void kernel_launch(void* const* d_in, const int* in_sizes, int n_in,
                              void* d_out, int out_size, void* d_ws, size_t ws_size,
                              hipStream_t stream)
{
    const float* x      = (const float*)d_in[0];
    const float* W_in   = (const float*)d_in[1];
    const float* conv_w = (const float*)d_in[2];
    const float* conv_b = (const float*)d_in[3];
    const float* A_log  = (const float*)d_in[4];
    const float* D_par  = (const float*)d_in[5];
    const float* W_x    = (const float*)d_in[6];
    const float* W_dt   = (const float*)d_in[7];
    const float* b_dt   = (const float*)d_in[8];
    const float* W_out  = (const float*)d_in[9];
    float* out = (float*)d_out;

    const size_t BT = (size_t)BATCH * TLEN;          // 8192
    float* ws = (float*)d_ws;
    float* xz   = ws;                                // BT * 2048
    float* x_in = xz + BT * (2 * DIM);               // BT * 1024 (later y_gated)
    float* dt   = x_in + BT * DIM;                   // BT * 1024
    float* BC   = dt + BT * DIM;                     // BT * 32

    // P/S live in the dead x-half columns of xz (rows 0..1023 / 1024..2047),
    // via ps_addr() strided mapping. z-half columns untouched.
    float* Pb = xz;                    // logical NC*B*DIM*16 entries
    float* Sb = xz + (size_t)1024 * 2048;  // rows 1024..2047

    // 1) xz = x @ W_in   (8192 x 2048 x 1024)
    {
        dim3 grid(2 * DIM / 64, BT / 64);
        gemm_f32<0><<<grid, 256, 0, stream>>>(x, W_in, nullptr, xz,
                                              (int)BT, 2 * DIM, DIM);
    }
    // 2) conv + silu -> x_in   (x-half of xz is dead afterwards)
    {
        size_t total = BT * DIM;
        conv_silu_kernel<<<(int)(total / 256), 256, 0, stream>>>(xz, conv_w, conv_b, x_in);
    }
    // 3) dt = softplus(x_in @ W_dt + b_dt)
    {
        dim3 grid(DIM / 64, BT / 64);
        gemm_f32<1><<<grid, 256, 0, stream>>>(x_in, W_dt, b_dt, dt,
                                              (int)BT, DIM, DIM);
    }
    // 4) BC = x_in @ W_x
    {
        bc_kernel<<<(int)(BT / 8), 256, 0, stream>>>(x_in, W_x, BC);
    }
    // 5) chunked parallel scan
    {
        int grid_ac = BATCH * NC * (DIM / 16);       // 4096 blocks
        scan_pass_a<<<grid_ac, 256, 0, stream>>>(dt, BC, x_in, A_log, Pb, Sb);
        scan_pass_b<<<(BATCH * DIM * DSTATE) / 256, 256, 0, stream>>>(Pb, Sb);
        scan_pass_c<<<grid_ac, 256, 0, stream>>>(dt, BC, xz, A_log, D_par, Pb, x_in);
    }
    // 6) out = y_gated @ W_out
    {
        dim3 grid(DIM / 64, BT / 64);
        gemm_f32<0><<<grid, 256, 0, stream>>>(x_in, W_out, nullptr, out,
                                              (int)BT, DIM, DIM);
    }
}

// Round 3
// 780.771 us; speedup vs baseline: 5.2026x; 1.8128x over previous
//
#include <hip/hip_runtime.h>
#include <math.h>

#define DIM 1024
#define DSTATE 16
#define DCONV 4
#define BATCH 2
#define TLEN 4096
#define NC 32            // time chunks
#define LC (TLEN / NC)   // 128 steps per chunk

typedef short s16x8 __attribute__((ext_vector_type(8)));
typedef float f32x4 __attribute__((ext_vector_type(4)));

__device__ __forceinline__ unsigned short f32_to_bf16(float f) {
    unsigned int u = __float_as_uint(f);
    u += 0x7fffu + ((u >> 16) & 1u);
    return (unsigned short)(u >> 16);
}
__device__ __forceinline__ float bf16_to_f32(unsigned short s) {
    return __uint_as_float(((unsigned int)s) << 16);
}

__device__ __forceinline__ void async16(const void* g, void* l) {
    __builtin_amdgcn_global_load_lds(
        (const __attribute__((address_space(1))) void*)g,
        (__attribute__((address_space(3))) void*)l, 16, 0, 0);
}

// Strided index into dead x-half columns of xz (for P/S chunk-scan scratch).
__device__ __forceinline__ size_t ps_addr(size_t i) {
    return ((i >> 10) << 11) | (i & 1023);
}

// ---------------------------------------------------------------------------
// Split-bf16 MFMA GEMM: C[M,N] = (Ah+Al)[M,K] @ (Bh+Bl)^T[N,K]
//   A given row-major [M][K] (hi/lo bf16); B given TRANSPOSED row-major [N][K].
//   C = Ah@Bh + Ah@Bl + Al@Bh (AlBl dropped, ~2^-18 rel).
// 128x128 block tile, BK=32, 256 threads (4 waves, 2x2 of 64x64).
// EPI: 0 = plain store, 1 = softplus(acc + bias[n]).
// ---------------------------------------------------------------------------
template <int EPI>
__global__ __launch_bounds__(256) void gemm_bf16s(
    const unsigned short* __restrict__ Ah, const unsigned short* __restrict__ Al,
    const unsigned short* __restrict__ Bh, const unsigned short* __restrict__ Bl,
    const float* __restrict__ bias, float* __restrict__ C,
    int M, int N, int K)
{
    __shared__ unsigned short sAh[128][32];
    __shared__ unsigned short sAl[128][32];
    __shared__ unsigned short sBh[128][32];
    __shared__ unsigned short sBl[128][32];

    const int tid  = threadIdx.x;
    const int lane = tid & 63;
    const int w    = tid >> 6;        // wave 0..3
    const int wm   = (w >> 1) * 64;   // wave m-offset in tile
    const int wn   = (w & 1) * 64;    // wave n-offset in tile
    const int m0   = blockIdx.y * 128;
    const int n0   = blockIdx.x * 128;

    f32x4 acc[4][4];
#pragma unroll
    for (int i = 0; i < 4; ++i)
#pragma unroll
        for (int j = 0; j < 4; ++j) acc[i][j] = (f32x4){0.f, 0.f, 0.f, 0.f};

    // staging: wave w covers tile rows [w*16, w*16+16) and +64; lane i/4 = row,
    // (i&3)*8 = k-element offset; LDS dst = uniform base + lane*16B.
    const int srow  = w * 16 + (lane >> 2);
    const int skoff = (lane & 3) * 8;
    const size_t aRow0 = (size_t)(m0 + srow) * K;
    const size_t aRow1 = (size_t)(m0 + srow + 64) * K;
    const size_t bRow0 = (size_t)(n0 + srow) * K;
    const size_t bRow1 = (size_t)(n0 + srow + 64) * K;

    const int frow = lane & 15;        // m (or n) within 16-tile
    const int fqd  = (lane >> 4) * 8;  // k-offset of this lane's 8 elements

    for (int k0 = 0; k0 < K; k0 += 32) {
        __syncthreads();
        async16(&Ah[aRow0 + k0 + skoff], &sAh[w * 16][0]);
        async16(&Ah[aRow1 + k0 + skoff], &sAh[64 + w * 16][0]);
        async16(&Al[aRow0 + k0 + skoff], &sAl[w * 16][0]);
        async16(&Al[aRow1 + k0 + skoff], &sAl[64 + w * 16][0]);
        async16(&Bh[bRow0 + k0 + skoff], &sBh[w * 16][0]);
        async16(&Bh[bRow1 + k0 + skoff], &sBh[64 + w * 16][0]);
        async16(&Bl[bRow0 + k0 + skoff], &sBl[w * 16][0]);
        async16(&Bl[bRow1 + k0 + skoff], &sBl[64 + w * 16][0]);
        __syncthreads();

        s16x8 fah[4], fal[4], fbh[4], fbl[4];
#pragma unroll
        for (int i = 0; i < 4; ++i) {
            fah[i] = *(const s16x8*)&sAh[wm + i * 16 + frow][fqd];
            fal[i] = *(const s16x8*)&sAl[wm + i * 16 + frow][fqd];
            fbh[i] = *(const s16x8*)&sBh[wn + i * 16 + frow][fqd];
            fbl[i] = *(const s16x8*)&sBl[wn + i * 16 + frow][fqd];
        }
#pragma unroll
        for (int mi = 0; mi < 4; ++mi)
#pragma unroll
            for (int ni = 0; ni < 4; ++ni) {
                acc[mi][ni] = __builtin_amdgcn_mfma_f32_16x16x32_bf16(
                    fah[mi], fbh[ni], acc[mi][ni], 0, 0, 0);
                acc[mi][ni] = __builtin_amdgcn_mfma_f32_16x16x32_bf16(
                    fah[mi], fbl[ni], acc[mi][ni], 0, 0, 0);
                acc[mi][ni] = __builtin_amdgcn_mfma_f32_16x16x32_bf16(
                    fal[mi], fbh[ni], acc[mi][ni], 0, 0, 0);
            }
    }

    // epilogue: C/D layout col=lane&15, row=(lane>>4)*4+reg  [m89/m91 verified]
    const int erow = (lane >> 4) * 4;
    const int ecol = lane & 15;
#pragma unroll
    for (int mi = 0; mi < 4; ++mi)
#pragma unroll
        for (int ni = 0; ni < 4; ++ni) {
            const int col = n0 + wn + ni * 16 + ecol;
            const float bv = (EPI == 1) ? bias[col] : 0.f;
#pragma unroll
            for (int r = 0; r < 4; ++r) {
                const int row = m0 + wm + mi * 16 + erow + r;
                float v = acc[mi][ni][r];
                if (EPI == 1) {
                    v += bv;
                    v = (v > 20.f) ? v : log1pf(__expf(v));
                }
                C[(size_t)row * N + col] = v;
            }
        }
}

// ---------------------------------------------------------------------------
// f32 -> (hi, lo) bf16 split, elementwise.
// ---------------------------------------------------------------------------
__global__ __launch_bounds__(256) void split_kernel(
    const float* __restrict__ src, unsigned short* __restrict__ h,
    unsigned short* __restrict__ l)
{
    size_t i = (size_t)blockIdx.x * 256 + threadIdx.x;
    float v = src[i];
    unsigned short hv = f32_to_bf16(v);
    h[i] = hv;
    l[i] = f32_to_bf16(v - bf16_to_f32(hv));
}

// ---------------------------------------------------------------------------
// W[K][N] f32 -> transposed split Th/Tl[N][K] bf16 (LDS 32x32 tile transpose).
// ---------------------------------------------------------------------------
__global__ __launch_bounds__(256) void split_transpose_kernel(
    const float* __restrict__ W, unsigned short* __restrict__ Th,
    unsigned short* __restrict__ Tl, int Kdim, int Ndim)
{
    __shared__ float tile[32][33];
    const int n0 = blockIdx.x * 32;
    const int k0 = blockIdx.y * 32;
    const int tx = threadIdx.x & 31;
    const int ty = threadIdx.x >> 5;   // 0..7
    for (int r = ty; r < 32; r += 8)
        tile[r][tx] = W[(size_t)(k0 + r) * Ndim + n0 + tx];
    __syncthreads();
    for (int r = ty; r < 32; r += 8) {
        float v = tile[tx][r];                       // = W[k0+tx][n0+r]
        unsigned short hv = f32_to_bf16(v);
        size_t o = (size_t)(n0 + r) * Kdim + k0 + tx;
        Th[o] = hv;
        Tl[o] = f32_to_bf16(v - bf16_to_f32(hv));
    }
}

// ---------------------------------------------------------------------------
// Depthwise causal conv (window 4) + bias + SiLU; writes f32 + bf16 hi/lo.
// ---------------------------------------------------------------------------
__global__ __launch_bounds__(256) void conv_silu_kernel(
    const float* __restrict__ xz, const float* __restrict__ conv_w,
    const float* __restrict__ conv_b, float* __restrict__ x_in,
    unsigned short* __restrict__ xh, unsigned short* __restrict__ xl)
{
    size_t idx = (size_t)blockIdx.x * 256 + threadIdx.x;
    int d = (int)(idx & (DIM - 1));
    size_t bt = idx >> 10;
    int t = (int)(bt & (TLEN - 1));

    float acc = conv_b[d];
#pragma unroll
    for (int k = 0; k < DCONV; ++k) {
        int tt = t - (DCONV - 1) + k;
        if (tt >= 0) {
            acc = fmaf(xz[(bt - (DCONV - 1) + k) * (2 * DIM) + d],
                       conv_w[d * DCONV + k], acc);
        }
    }
    float s = acc / (1.f + __expf(-acc));
    x_in[idx] = s;
    unsigned short hv = f32_to_bf16(s);
    xh[idx] = hv;
    xl[idx] = f32_to_bf16(s - bf16_to_f32(hv));
}

// ---------------------------------------------------------------------------
// BC = x_in(B*T, DIM) @ W_x(DIM, 2*DSTATE)
// ---------------------------------------------------------------------------
__global__ __launch_bounds__(256) void bc_kernel(
    const float* __restrict__ x_in, const float* __restrict__ W_x,
    float* __restrict__ BC)
{
    int n = threadIdx.x & 31;
    int ml = threadIdx.x >> 5;
    size_t m = (size_t)blockIdx.x * 8 + ml;
    const float* xr = &x_in[m * DIM];
    float acc = 0.f;
#pragma unroll 4
    for (int k = 0; k < DIM; ++k) {
        acc = fmaf(xr[k], W_x[k * (2 * DSTATE) + n], acc);
    }
    BC[m * (2 * DSTATE) + n] = acc;
}

// ---------------------------------------------------------------------------
// Scan pass A: per (b, d, n, chunk): local scan from h=0 -> S, decay prod -> P
// ---------------------------------------------------------------------------
__global__ __launch_bounds__(256) void scan_pass_a(
    const float* __restrict__ dt, const float* __restrict__ BC,
    const float* __restrict__ x_in, const float* __restrict__ A_log,
    float* __restrict__ Pb, float* __restrict__ Sb)
{
    const int tid = threadIdx.x;
    const int n = tid & 15;
    const int g = tid >> 4;
    int blk = blockIdx.x;
    const int dblk = blk & 63;  blk >>= 6;
    const int c = blk & (NC - 1); blk >>= 5;
    const int b = blk;
    const int d = dblk * 16 + g;

    const float A = -__expf(A_log[d * DSTATE + n]);

    float h = 0.f, sdt = 0.f;
    const size_t base = (size_t)b * TLEN + (size_t)c * LC;
    for (int t = 0; t < LC; ++t) {
        const size_t r = base + t;
        const float dtv = dt[r * DIM + d];
        const float xv  = x_in[r * DIM + d];
        const float Bv  = BC[r * (2 * DSTATE) + n];
        sdt += dtv;
        const float a = __expf(dtv * A);
        h = fmaf(a, h, dtv * Bv * xv);
    }
    const size_t o = (((size_t)c * BATCH + b) * DIM + d) * DSTATE + n;
    Pb[ps_addr(o)] = __expf(A * sdt);
    Sb[ps_addr(o)] = h;
}

// ---------------------------------------------------------------------------
// Scan pass B: sequential combine over NC chunks; P[c] <- incoming state.
// ---------------------------------------------------------------------------
__global__ __launch_bounds__(256) void scan_pass_b(
    float* __restrict__ Pb, const float* __restrict__ Sb)
{
    const size_t idx = (size_t)blockIdx.x * 256 + threadIdx.x;
    float h = 0.f;
#pragma unroll 4
    for (int c = 0; c < NC; ++c) {
        const size_t o = (size_t)c * (BATCH * DIM * DSTATE) + idx;
        const size_t a = ps_addr(o);
        const float p = Pb[a];
        const float s = Sb[a];
        Pb[a] = h;
        h = fmaf(p, h, s);
    }
}

// ---------------------------------------------------------------------------
// Scan pass C: seeded local scan; y reduce over n, D skip, z-gate;
// writes y as bf16 hi/lo (GEMM3 input).
// ---------------------------------------------------------------------------
__global__ __launch_bounds__(256) void scan_pass_c(
    const float* __restrict__ dt, const float* __restrict__ BC,
    const float* __restrict__ xz, const float* __restrict__ A_log,
    const float* __restrict__ D_param, const float* __restrict__ Hin,
    const float* __restrict__ x_in,
    unsigned short* __restrict__ yh, unsigned short* __restrict__ yl)
{
    const int tid = threadIdx.x;
    const int n = tid & 15;
    const int g = tid >> 4;
    int blk = blockIdx.x;
    const int dblk = blk & 63;  blk >>= 6;
    const int c = blk & (NC - 1); blk >>= 5;
    const int b = blk;
    const int d = dblk * 16 + g;

    const float A = -__expf(A_log[d * DSTATE + n]);
    const float Dp = D_param[d];

    const size_t o = (((size_t)c * BATCH + b) * DIM + d) * DSTATE + n;
    float h = Hin[ps_addr(o)];

    const size_t base = (size_t)b * TLEN + (size_t)c * LC;
    for (int t = 0; t < LC; ++t) {
        const size_t r = base + t;
        const float dtv = dt[r * DIM + d];
        const float xv  = x_in[r * DIM + d];
        const float Bv  = BC[r * (2 * DSTATE) + n];
        const float Cv  = BC[r * (2 * DSTATE) + DSTATE + n];

        const float a = __expf(dtv * A);
        h = fmaf(a, h, dtv * Bv * xv);

        float p = h * Cv;
        p += __shfl_xor(p, 1, 16);
        p += __shfl_xor(p, 2, 16);
        p += __shfl_xor(p, 4, 16);
        p += __shfl_xor(p, 8, 16);

        if (n == 0) {
            const float zv = xz[r * (2 * DIM) + DIM + d];
            const float y = p + Dp * xv;
            const float sig = 1.f / (1.f + __expf(-zv));
            const float yg = y * (zv * sig);
            unsigned short hv = f32_to_bf16(yg);
            yh[r * DIM + d] = hv;
            yl[r * DIM + d] = f32_to_bf16(yg - bf16_to_f32(hv));
        }
    }
}

// ---------------------------------------------------------------------------
// Launch
// ---------------------------------------------------------------------------
extern "C" void kernel_launch(void* const* d_in, const int* in_sizes, int n_in,
                              void* d_out, int out_size, void* d_ws, size_t ws_size,
                              hipStream_t stream)
{
    const float* x      = (const float*)d_in[0];
    const float* W_in   = (const float*)d_in[1];
    const float* conv_w = (const float*)d_in[2];
    const float* conv_b = (const float*)d_in[3];
    const float* A_log  = (const float*)d_in[4];
    const float* D_par  = (const float*)d_in[5];
    const float* W_x    = (const float*)d_in[6];
    const float* W_dt   = (const float*)d_in[7];
    const float* b_dt   = (const float*)d_in[8];
    const float* W_out  = (const float*)d_in[9];
    float* out = (float*)d_out;

    const size_t BT = (size_t)BATCH * TLEN;          // 8192
    float* ws = (float*)d_ws;
    float* xz   = ws;                                // BT*2048 f32 (64 MB)
    float* x_in = xz + BT * (2 * DIM);               // BT*1024 f32 (32 MB)
    float* dt   = x_in + BT * DIM;                   // BT*1024 f32 (32 MB)
    float* BCb  = dt + BT * DIM;                     // BT*32   f32 (1 MB)

    // bf16 region (32 MB), reused sequentially: Xh/Xl -> xin_h/l -> y_h/l
    unsigned short* bfA  = (unsigned short*)(BCb + BT * 32);
    unsigned short* bfAh = bfA;                      // BT*1024 shorts
    unsigned short* bfAl = bfA + BT * DIM;
    // transposed split weights (16 MB total)
    unsigned short* WinTh  = bfA + 2 * BT * DIM;           // 2048*1024
    unsigned short* WinTl  = WinTh + (size_t)2048 * 1024;
    unsigned short* WdtTh  = WinTl + (size_t)2048 * 1024;  // 1024*1024
    unsigned short* WdtTl  = WdtTh + (size_t)1024 * 1024;
    unsigned short* WoutTh = WdtTl + (size_t)1024 * 1024;
    unsigned short* WoutTl = WoutTh + (size_t)1024 * 1024;

    // P/S chunk-scan scratch in dead x-half columns of xz (via ps_addr).
    float* Pb = xz;
    float* Sb = xz + (size_t)1024 * 2048;

    // 0) splits
    split_kernel<<<(int)(BT * DIM / 256), 256, 0, stream>>>(x, bfAh, bfAl);
    split_transpose_kernel<<<dim3(2048 / 32, 1024 / 32), 256, 0, stream>>>(
        W_in, WinTh, WinTl, 1024, 2048);
    split_transpose_kernel<<<dim3(1024 / 32, 1024 / 32), 256, 0, stream>>>(
        W_dt, WdtTh, WdtTl, 1024, 1024);
    split_transpose_kernel<<<dim3(1024 / 32, 1024 / 32), 256, 0, stream>>>(
        W_out, WoutTh, WoutTl, 1024, 1024);

    // 1) xz = x @ W_in
    gemm_bf16s<0><<<dim3(2048 / 128, BT / 128), 256, 0, stream>>>(
        bfAh, bfAl, WinTh, WinTl, nullptr, xz, (int)BT, 2 * DIM, DIM);

    // 2) conv + silu -> x_in f32 + bf16 hi/lo (overwrites Xh/Xl, now dead)
    conv_silu_kernel<<<(int)(BT * DIM / 256), 256, 0, stream>>>(
        xz, conv_w, conv_b, x_in, bfAh, bfAl);

    // 3) dt = softplus(x_in @ W_dt + b_dt)
    gemm_bf16s<1><<<dim3(1024 / 128, BT / 128), 256, 0, stream>>>(
        bfAh, bfAl, WdtTh, WdtTl, b_dt, dt, (int)BT, DIM, DIM);

    // 4) BC = x_in @ W_x  (f32)
    bc_kernel<<<(int)(BT / 8), 256, 0, stream>>>(x_in, W_x, BCb);

    // 5) chunked parallel scan; pass C writes y hi/lo (overwrites xin h/l, dead)
    {
        int grid_ac = BATCH * NC * (DIM / 16);
        scan_pass_a<<<grid_ac, 256, 0, stream>>>(dt, BCb, x_in, A_log, Pb, Sb);
        scan_pass_b<<<(BATCH * DIM * DSTATE) / 256, 256, 0, stream>>>(Pb, Sb);
        scan_pass_c<<<grid_ac, 256, 0, stream>>>(dt, BCb, xz, A_log, D_par, Pb,
                                                 x_in, bfAh, bfAl);
    }

    // 6) out = y @ W_out
    gemm_bf16s<0><<<dim3(1024 / 128, BT / 128), 256, 0, stream>>>(
        bfAh, bfAl, WoutTh, WoutTl, nullptr, out, (int)BT, DIM, DIM);
}

// Round 4
// 549.385 us; speedup vs baseline: 7.3938x; 1.4212x over previous
//
#include <hip/hip_runtime.h>
#include <math.h>

#define DIM 1024
#define DSTATE 16
#define DCONV 4
#define BATCH 2
#define TLEN 4096
#define NC 128           // time chunks
#define LC (TLEN / NC)   // 32 steps per chunk

typedef short s16x8 __attribute__((ext_vector_type(8)));
typedef float f32x4 __attribute__((ext_vector_type(4)));

__device__ __forceinline__ unsigned short f32_to_bf16(float f) {
    unsigned int u = __float_as_uint(f);
    u += 0x7fffu + ((u >> 16) & 1u);
    return (unsigned short)(u >> 16);
}
__device__ __forceinline__ float bf16_to_f32(unsigned short s) {
    return __uint_as_float(((unsigned int)s) << 16);
}

__device__ __forceinline__ void async16(const void* g, void* l) {
    __builtin_amdgcn_global_load_lds(
        (const __attribute__((address_space(1))) void*)g,
        (__attribute__((address_space(3))) void*)l, 16, 0, 0);
}

// Strided index into dead x-half columns of xz (P/S chunk-scan scratch).
// Logical float index i -> physical float offset: row (i>>10), col (i&1023).
__device__ __forceinline__ size_t ps_addr(size_t i) {
    return ((i >> 10) << 11) | (i & 1023);
}

// ---------------------------------------------------------------------------
// Split-bf16 MFMA GEMM: C[M,N] = (Ah+Al)[M,K] @ (Bh+Bl)^T[N,K]
// 128x128 tile, BK=32, 256 threads (4 waves, 2x2 of 64x64), 16x16x32 MFMA.
// EPI: 0 = plain store (ldc=N), 1 = softplus(acc+bias[n]),
//      2 = combined: cols [0,1024) -> softplus+bias into C (ldc=DIM),
//                    cols [1024,1056) -> plain f32 into C2 (ldc=32),
//                    cols >= 1056    -> skip (zero-pad tiles).
// ---------------------------------------------------------------------------
template <int EPI>
__global__ __launch_bounds__(256) void gemm_bf16s(
    const unsigned short* __restrict__ Ah, const unsigned short* __restrict__ Al,
    const unsigned short* __restrict__ Bh, const unsigned short* __restrict__ Bl,
    const float* __restrict__ bias, float* __restrict__ C,
    float* __restrict__ C2, int M, int N, int K)
{
    __shared__ unsigned short sAh[128][32];
    __shared__ unsigned short sAl[128][32];
    __shared__ unsigned short sBh[128][32];
    __shared__ unsigned short sBl[128][32];

    const int tid  = threadIdx.x;
    const int lane = tid & 63;
    const int w    = tid >> 6;
    const int wm   = (w >> 1) * 64;
    const int wn   = (w & 1) * 64;
    const int m0   = blockIdx.y * 128;
    const int n0   = blockIdx.x * 128;

    f32x4 acc[4][4];
#pragma unroll
    for (int i = 0; i < 4; ++i)
#pragma unroll
        for (int j = 0; j < 4; ++j) acc[i][j] = (f32x4){0.f, 0.f, 0.f, 0.f};

    const int srow  = w * 16 + (lane >> 2);
    const int skoff = (lane & 3) * 8;
    const size_t aRow0 = (size_t)(m0 + srow) * K;
    const size_t aRow1 = (size_t)(m0 + srow + 64) * K;
    const size_t bRow0 = (size_t)(n0 + srow) * K;
    const size_t bRow1 = (size_t)(n0 + srow + 64) * K;

    const int frow = lane & 15;
    const int fqd  = (lane >> 4) * 8;

    for (int k0 = 0; k0 < K; k0 += 32) {
        __syncthreads();
        async16(&Ah[aRow0 + k0 + skoff], &sAh[w * 16][0]);
        async16(&Ah[aRow1 + k0 + skoff], &sAh[64 + w * 16][0]);
        async16(&Al[aRow0 + k0 + skoff], &sAl[w * 16][0]);
        async16(&Al[aRow1 + k0 + skoff], &sAl[64 + w * 16][0]);
        async16(&Bh[bRow0 + k0 + skoff], &sBh[w * 16][0]);
        async16(&Bh[bRow1 + k0 + skoff], &sBh[64 + w * 16][0]);
        async16(&Bl[bRow0 + k0 + skoff], &sBl[w * 16][0]);
        async16(&Bl[bRow1 + k0 + skoff], &sBl[64 + w * 16][0]);
        __syncthreads();

        s16x8 fah[4], fal[4], fbh[4], fbl[4];
#pragma unroll
        for (int i = 0; i < 4; ++i) {
            fah[i] = *(const s16x8*)&sAh[wm + i * 16 + frow][fqd];
            fal[i] = *(const s16x8*)&sAl[wm + i * 16 + frow][fqd];
            fbh[i] = *(const s16x8*)&sBh[wn + i * 16 + frow][fqd];
            fbl[i] = *(const s16x8*)&sBl[wn + i * 16 + frow][fqd];
        }
#pragma unroll
        for (int mi = 0; mi < 4; ++mi)
#pragma unroll
            for (int ni = 0; ni < 4; ++ni) {
                acc[mi][ni] = __builtin_amdgcn_mfma_f32_16x16x32_bf16(
                    fah[mi], fbh[ni], acc[mi][ni], 0, 0, 0);
                acc[mi][ni] = __builtin_amdgcn_mfma_f32_16x16x32_bf16(
                    fah[mi], fbl[ni], acc[mi][ni], 0, 0, 0);
                acc[mi][ni] = __builtin_amdgcn_mfma_f32_16x16x32_bf16(
                    fal[mi], fbh[ni], acc[mi][ni], 0, 0, 0);
            }
    }

    // C/D layout: col=lane&15, row=(lane>>4)*4+reg
    const int erow = (lane >> 4) * 4;
    const int ecol = lane & 15;
#pragma unroll
    for (int mi = 0; mi < 4; ++mi)
#pragma unroll
        for (int ni = 0; ni < 4; ++ni) {
            const int colbase = n0 + wn + ni * 16;   // wave-uniform
            if (EPI == 2 && colbase >= 1024 + 2 * DSTATE) continue;
            const int col = colbase + ecol;
            if (EPI == 2 && colbase >= 1024) {
#pragma unroll
                for (int r = 0; r < 4; ++r) {
                    const int row = m0 + wm + mi * 16 + erow + r;
                    C2[(size_t)row * (2 * DSTATE) + (col - 1024)] = acc[mi][ni][r];
                }
            } else {
                const float bv = (EPI >= 1) ? bias[col] : 0.f;
                const int ldc = (EPI == 2) ? DIM : N;
#pragma unroll
                for (int r = 0; r < 4; ++r) {
                    const int row = m0 + wm + mi * 16 + erow + r;
                    float v = acc[mi][ni][r];
                    if (EPI >= 1) {
                        v += bv;
                        v = (v > 20.f) ? v : log1pf(__expf(v));
                    }
                    C[(size_t)row * ldc + col] = v;
                }
            }
        }
}

// ---------------------------------------------------------------------------
// f32 -> (hi, lo) bf16 split, elementwise.
// ---------------------------------------------------------------------------
__global__ __launch_bounds__(256) void split_kernel(
    const float* __restrict__ src, unsigned short* __restrict__ h,
    unsigned short* __restrict__ l)
{
    size_t i = (size_t)blockIdx.x * 256 + threadIdx.x;
    float v = src[i];
    unsigned short hv = f32_to_bf16(v);
    h[i] = hv;
    l[i] = f32_to_bf16(v - bf16_to_f32(hv));
}

// ---------------------------------------------------------------------------
// W[K][N] f32 -> transposed split Th/Tl[N][K] bf16 (LDS 32x32 tile transpose).
// ---------------------------------------------------------------------------
__global__ __launch_bounds__(256) void split_transpose_kernel(
    const float* __restrict__ W, unsigned short* __restrict__ Th,
    unsigned short* __restrict__ Tl, int Kdim, int Ndim)
{
    __shared__ float tile[32][33];
    const int n0 = blockIdx.x * 32;
    const int k0 = blockIdx.y * 32;
    const int tx = threadIdx.x & 31;
    const int ty = threadIdx.x >> 5;
    for (int r = ty; r < 32; r += 8)
        tile[r][tx] = W[(size_t)(k0 + r) * Ndim + n0 + tx];
    __syncthreads();
    for (int r = ty; r < 32; r += 8) {
        float v = tile[tx][r];
        unsigned short hv = f32_to_bf16(v);
        size_t o = (size_t)(n0 + r) * Kdim + k0 + tx;
        Th[o] = hv;
        Tl[o] = f32_to_bf16(v - bf16_to_f32(hv));
    }
}

// ---------------------------------------------------------------------------
// Depthwise causal conv (window 4) + bias + SiLU; writes f32 + bf16 hi/lo.
// ---------------------------------------------------------------------------
__global__ __launch_bounds__(256) void conv_silu_kernel(
    const float* __restrict__ xz, const float* __restrict__ conv_w,
    const float* __restrict__ conv_b, float* __restrict__ x_in,
    unsigned short* __restrict__ xh, unsigned short* __restrict__ xl)
{
    size_t idx = (size_t)blockIdx.x * 256 + threadIdx.x;
    int d = (int)(idx & (DIM - 1));
    size_t bt = idx >> 10;
    int t = (int)(bt & (TLEN - 1));

    float acc = conv_b[d];
#pragma unroll
    for (int k = 0; k < DCONV; ++k) {
        int tt = t - (DCONV - 1) + k;
        if (tt >= 0) {
            acc = fmaf(xz[(bt - (DCONV - 1) + k) * (2 * DIM) + d],
                       conv_w[d * DCONV + k], acc);
        }
    }
    float s = acc / (1.f + __expf(-acc));
    x_in[idx] = s;
    unsigned short hv = f32_to_bf16(s);
    xh[idx] = hv;
    xl[idx] = f32_to_bf16(s - bf16_to_f32(hv));
}

// ---------------------------------------------------------------------------
// Scan pass A: one lane per (b,d); h[16] in VGPRs; local scan from h=0.
// Stores S = h_local_end[16], P = exp(A_n * sum_dt). B staged in LDS.
// Grid: BATCH * NC * (DIM/256), block 256.
// ---------------------------------------------------------------------------
__global__ __launch_bounds__(256) void scan_pass_a(
    const float* __restrict__ dt, const float* __restrict__ BC,
    const float* __restrict__ x_in, const float* __restrict__ A_log,
    float* __restrict__ Pb, float* __restrict__ Sb)
{
    __shared__ float sB[LC][DSTATE];
    const int tid = threadIdx.x;
    int blk = blockIdx.x;
    const int dt4 = blk & 3;  blk >>= 2;
    const int c = blk & (NC - 1); blk >>= 7;
    const int b = blk;
    const int d = dt4 * 256 + tid;
    const size_t base = (size_t)b * TLEN + (size_t)c * LC;

    if (tid < LC * DSTATE / 4) {
        const int row = tid >> 2, c4 = tid & 3;
        *(f32x4*)&sB[row][c4 * 4] =
            *(const f32x4*)&BC[(base + row) * (2 * DSTATE) + c4 * 4];
    }

    float A[DSTATE];
#pragma unroll
    for (int q = 0; q < 4; ++q) {
        f32x4 v = *(const f32x4*)&A_log[(size_t)d * DSTATE + q * 4];
        A[q * 4 + 0] = -__expf(v.x); A[q * 4 + 1] = -__expf(v.y);
        A[q * 4 + 2] = -__expf(v.z); A[q * 4 + 3] = -__expf(v.w);
    }
    __syncthreads();

    float h[DSTATE];
#pragma unroll
    for (int n = 0; n < DSTATE; ++n) h[n] = 0.f;
    float sdt = 0.f;

    for (int t = 0; t < LC; ++t) {
        const float dtv = dt[(base + t) * DIM + d];
        const float xv  = x_in[(base + t) * DIM + d];
        sdt += dtv;
        const float dbx = dtv * xv;
#pragma unroll
        for (int n = 0; n < DSTATE; ++n) {
            const float a = __expf(dtv * A[n]);
            h[n] = fmaf(a, h[n], dbx * sB[t][n]);
        }
    }

    const size_t po = ps_addr((((size_t)c * BATCH + b) * DIM + d) * DSTATE);
#pragma unroll
    for (int q = 0; q < 4; ++q) {
        f32x4 pv;
        pv.x = __expf(A[q * 4 + 0] * sdt);
        pv.y = __expf(A[q * 4 + 1] * sdt);
        pv.z = __expf(A[q * 4 + 2] * sdt);
        pv.w = __expf(A[q * 4 + 3] * sdt);
        *(f32x4*)&Pb[po + q * 4] = pv;
        *(f32x4*)&Sb[po + q * 4] = *(f32x4*)&h[q * 4];
    }
}

// ---------------------------------------------------------------------------
// Scan pass B: per (b,d,n): sequential combine over NC chunks.
// P[c] <- incoming state of chunk c.
// ---------------------------------------------------------------------------
__global__ __launch_bounds__(256) void scan_pass_b(
    float* __restrict__ Pb, const float* __restrict__ Sb)
{
    const size_t idx = (size_t)blockIdx.x * 256 + threadIdx.x;  // B*DIM*16
    float h = 0.f;
#pragma unroll 4
    for (int c = 0; c < NC; ++c) {
        const size_t o = (size_t)c * (BATCH * DIM * DSTATE) + idx;
        const size_t a = ps_addr(o);
        const float p = Pb[a];
        const float s = Sb[a];
        Pb[a] = h;
        h = fmaf(p, h, s);
    }
}

// ---------------------------------------------------------------------------
// Scan pass C: one lane per (b,d); seeded local scan; y = sum_n h*C + D*x;
// fused z-gate; writes y as bf16 hi/lo. B,C staged in LDS.
// ---------------------------------------------------------------------------
__global__ __launch_bounds__(256) void scan_pass_c(
    const float* __restrict__ dt, const float* __restrict__ BC,
    const float* __restrict__ xz, const float* __restrict__ A_log,
    const float* __restrict__ D_param, const float* __restrict__ Hin,
    const float* __restrict__ x_in,
    unsigned short* __restrict__ yh, unsigned short* __restrict__ yl)
{
    __shared__ float sB[LC][DSTATE];
    __shared__ float sC[LC][DSTATE];
    const int tid = threadIdx.x;
    int blk = blockIdx.x;
    const int dt4 = blk & 3;  blk >>= 2;
    const int c = blk & (NC - 1); blk >>= 7;
    const int b = blk;
    const int d = dt4 * 256 + tid;
    const size_t base = (size_t)b * TLEN + (size_t)c * LC;

    if (tid < 128) {
        const int row = tid >> 2, c4 = tid & 3;
        *(f32x4*)&sB[row][c4 * 4] =
            *(const f32x4*)&BC[(base + row) * (2 * DSTATE) + c4 * 4];
    } else {
        const int sj = tid - 128;
        const int row = sj >> 2, c4 = sj & 3;
        *(f32x4*)&sC[row][c4 * 4] =
            *(const f32x4*)&BC[(base + row) * (2 * DSTATE) + DSTATE + c4 * 4];
    }

    float A[DSTATE];
#pragma unroll
    for (int q = 0; q < 4; ++q) {
        f32x4 v = *(const f32x4*)&A_log[(size_t)d * DSTATE + q * 4];
        A[q * 4 + 0] = -__expf(v.x); A[q * 4 + 1] = -__expf(v.y);
        A[q * 4 + 2] = -__expf(v.z); A[q * 4 + 3] = -__expf(v.w);
    }
    const float Dp = D_param[d];

    float h[DSTATE];
    const size_t po = ps_addr((((size_t)c * BATCH + b) * DIM + d) * DSTATE);
#pragma unroll
    for (int q = 0; q < 4; ++q)
        *(f32x4*)&h[q * 4] = *(const f32x4*)&Hin[po + q * 4];
    __syncthreads();

    for (int t = 0; t < LC; ++t) {
        const float dtv = dt[(base + t) * DIM + d];
        const float xv  = x_in[(base + t) * DIM + d];
        const float zv  = xz[(base + t) * (2 * DIM) + DIM + d];
        const float dbx = dtv * xv;
        float y0 = 0.f, y1 = 0.f, y2 = 0.f, y3 = 0.f;
#pragma unroll
        for (int q = 0; q < 4; ++q) {
            float a0 = __expf(dtv * A[q * 4 + 0]);
            float a1 = __expf(dtv * A[q * 4 + 1]);
            float a2 = __expf(dtv * A[q * 4 + 2]);
            float a3 = __expf(dtv * A[q * 4 + 3]);
            h[q * 4 + 0] = fmaf(a0, h[q * 4 + 0], dbx * sB[t][q * 4 + 0]);
            h[q * 4 + 1] = fmaf(a1, h[q * 4 + 1], dbx * sB[t][q * 4 + 1]);
            h[q * 4 + 2] = fmaf(a2, h[q * 4 + 2], dbx * sB[t][q * 4 + 2]);
            h[q * 4 + 3] = fmaf(a3, h[q * 4 + 3], dbx * sB[t][q * 4 + 3]);
            y0 = fmaf(h[q * 4 + 0], sC[t][q * 4 + 0], y0);
            y1 = fmaf(h[q * 4 + 1], sC[t][q * 4 + 1], y1);
            y2 = fmaf(h[q * 4 + 2], sC[t][q * 4 + 2], y2);
            y3 = fmaf(h[q * 4 + 3], sC[t][q * 4 + 3], y3);
        }
        float y = (y0 + y1) + (y2 + y3) + Dp * xv;
        const float sig = 1.f / (1.f + __expf(-zv));
        const float yg = y * (zv * sig);
        unsigned short hv = f32_to_bf16(yg);
        yh[(base + t) * DIM + d] = hv;
        yl[(base + t) * DIM + d] = f32_to_bf16(yg - bf16_to_f32(hv));
    }
}

// ---------------------------------------------------------------------------
// Launch
// ---------------------------------------------------------------------------
extern "C" void kernel_launch(void* const* d_in, const int* in_sizes, int n_in,
                              void* d_out, int out_size, void* d_ws, size_t ws_size,
                              hipStream_t stream)
{
    const float* x      = (const float*)d_in[0];
    const float* W_in   = (const float*)d_in[1];
    const float* conv_w = (const float*)d_in[2];
    const float* conv_b = (const float*)d_in[3];
    const float* A_log  = (const float*)d_in[4];
    const float* D_par  = (const float*)d_in[5];
    const float* W_x    = (const float*)d_in[6];
    const float* W_dt   = (const float*)d_in[7];
    const float* b_dt   = (const float*)d_in[8];
    const float* W_out  = (const float*)d_in[9];
    float* out = (float*)d_out;

    const size_t BT = (size_t)BATCH * TLEN;          // 8192
    float* ws = (float*)d_ws;
    float* xz   = ws;                                // BT*2048 f32
    float* x_in = xz + BT * (2 * DIM);               // BT*1024 f32
    float* dtb  = x_in + BT * DIM;                   // BT*1024 f32
    float* BCb  = dtb + BT * DIM;                    // BT*32   f32

    unsigned short* bfAh = (unsigned short*)(BCb + BT * 2 * DSTATE);
    unsigned short* bfAl = bfAh + BT * DIM;
    unsigned short* WinTh = bfAl + BT * DIM;                 // 2048*1024
    unsigned short* WinTl = WinTh + (size_t)2048 * 1024;
    unsigned short* W2Th  = WinTl + (size_t)2048 * 1024;     // 1152*1024 (dt|Wx|pad)
    unsigned short* W2Tl  = W2Th + (size_t)1152 * 1024;
    unsigned short* WoutTh = W2Tl + (size_t)1152 * 1024;     // 1024*1024
    unsigned short* WoutTl = WoutTh + (size_t)1024 * 1024;

    // P/S chunk-scan scratch in dead x-half columns of xz (via ps_addr).
    // P: logical NC*B*DIM*16 floats -> xz rows 0..4095; S -> rows 4096..8191.
    float* Pb = xz;
    float* Sb = xz + (size_t)4096 * 2048;

    // 0) splits (input x; W_in; W_dt||W_x combined; W_out)
    split_kernel<<<(int)(BT * DIM / 256), 256, 0, stream>>>(x, bfAh, bfAl);
    split_transpose_kernel<<<dim3(2048 / 32, 1024 / 32), 256, 0, stream>>>(
        W_in, WinTh, WinTl, 1024, 2048);
    split_transpose_kernel<<<dim3(1024 / 32, 1024 / 32), 256, 0, stream>>>(
        W_dt, W2Th, W2Tl, 1024, 1024);
    split_transpose_kernel<<<dim3(1, 1024 / 32), 256, 0, stream>>>(
        W_x, W2Th + (size_t)1024 * 1024, W2Tl + (size_t)1024 * 1024, 1024, 32);
    split_transpose_kernel<<<dim3(1024 / 32, 1024 / 32), 256, 0, stream>>>(
        W_out, WoutTh, WoutTl, 1024, 1024);
    // pad rows 1056..1151 of W2T stay 0xAA-poisoned: tiny finite bf16 values,
    // their output tiles are skip-stored in the EPI=2 epilogue.

    // 1) xz = x @ W_in
    gemm_bf16s<0><<<dim3(2048 / 128, BT / 128), 256, 0, stream>>>(
        bfAh, bfAl, WinTh, WinTl, nullptr, xz, nullptr, (int)BT, 2 * DIM, DIM);

    // 2) conv + silu -> x_in f32 + bf16 hi/lo (overwrites Xh/Xl, now dead)
    conv_silu_kernel<<<(int)(BT * DIM / 256), 256, 0, stream>>>(
        xz, conv_w, conv_b, x_in, bfAh, bfAl);

    // 3) dt = softplus(x_in @ W_dt + b_dt)  AND  BC = x_in @ W_x  (fused)
    gemm_bf16s<2><<<dim3(1152 / 128, BT / 128), 256, 0, stream>>>(
        bfAh, bfAl, W2Th, W2Tl, b_dt, dtb, BCb, (int)BT, 1152, DIM);

    // 4) chunked parallel scan; pass C writes y hi/lo (over xin h/l, dead)
    {
        int grid_ac = BATCH * NC * (DIM / 256);      // 1024 blocks
        scan_pass_a<<<grid_ac, 256, 0, stream>>>(dtb, BCb, x_in, A_log, Pb, Sb);
        scan_pass_b<<<(BATCH * DIM * DSTATE) / 256, 256, 0, stream>>>(Pb, Sb);
        scan_pass_c<<<grid_ac, 256, 0, stream>>>(dtb, BCb, xz, A_log, D_par, Pb,
                                                 x_in, bfAh, bfAl);
    }

    // 5) out = y @ W_out
    gemm_bf16s<0><<<dim3(1024 / 128, BT / 128), 256, 0, stream>>>(
        bfAh, bfAl, WoutTh, WoutTl, nullptr, out, nullptr, (int)BT, DIM, DIM);
}